// Round 4
// baseline (88.109 us; speedup 1.0000x reference)
//
#include <hip/hip_runtime.h>

// KL(p||q) diagonal Gaussians -> scalar.
// Per float4: quad = sum (sp^2+(mp-mq)^2)/sq^2 ; prod = prod sp^2/sq^2
// contribution = 0.5*(quad - log(prod) - 4)   [1 log per 4 elements]
// 4 fp32 tensors x 33.5M elems = 512 MiB read; ~half L3-resident.
// Round 4: 2x unrolled grid-stride + explicit prefetch => ~16 loads in
// flight per thread (memory-latency hiding), 1 log / 4 elems.

#define RED_BLOCKS 2048
#define RED_THREADS 256

typedef float f32x4 __attribute__((ext_vector_type(4)));

__device__ __forceinline__ float wave_reduce_sum(float v) {
    #pragma unroll
    for (int off = 32; off > 0; off >>= 1)
        v += __shfl_down(v, off, 64);
    return v;
}

// per-float4 KL contribution: 4 rcp + 1 log
__device__ __forceinline__ float kl4(f32x4 mp, f32x4 sp, f32x4 mq, f32x4 sq) {
    float quad = 0.0f;
    float prod = 1.0f;
    #pragma unroll
    for (int k = 0; k < 4; ++k) {
        float sp2 = sp[k] * sp[k];
        float sq2 = sq[k] * sq[k];
        float d   = mp[k] - mq[k];
        float inv = __frcp_rn(sq2);
        quad += (sp2 + d * d) * inv;
        prod *= sp2 * inv;              // ratios in [0.028, 9] -> prod safe
    }
    return 0.5f * (quad - __logf(prod) - 4.0f);
}

__global__ __launch_bounds__(RED_THREADS) void kl_partial_kernel(
        const f32x4* __restrict__ pmu,
        const f32x4* __restrict__ psig,
        const f32x4* __restrict__ qmu,
        const f32x4* __restrict__ qsig,
        float* __restrict__ partial,
        long n4) {
    long idx    = (long)blockIdx.x * blockDim.x + threadIdx.x;
    long stride = (long)gridDim.x * blockDim.x;
    long step2  = 2 * stride;

    float acc = 0.0f;

    long full = n4 / step2;              // 8 at the reference shape
    if (full > 0) {
        long i = idx;
        long k = idx + stride;
        // prefetch iteration 0 (8 x 16B loads in flight)
        f32x4 a0 = __builtin_nontemporal_load(&pmu[i]);
        f32x4 b0 = psig[i];
        f32x4 c0 = __builtin_nontemporal_load(&qmu[i]);
        f32x4 d0 = qsig[i];
        f32x4 a1 = __builtin_nontemporal_load(&pmu[k]);
        f32x4 b1 = psig[k];
        f32x4 c1 = __builtin_nontemporal_load(&qmu[k]);
        f32x4 d1 = qsig[k];
        for (long it = 0; it < full - 1; ++it) {
            long j0 = i + step2;
            long j1 = k + step2;
            // issue next iteration's 8 loads before computing current
            f32x4 na0 = __builtin_nontemporal_load(&pmu[j0]);
            f32x4 nb0 = psig[j0];
            f32x4 nc0 = __builtin_nontemporal_load(&qmu[j0]);
            f32x4 nd0 = qsig[j0];
            f32x4 na1 = __builtin_nontemporal_load(&pmu[j1]);
            f32x4 nb1 = psig[j1];
            f32x4 nc1 = __builtin_nontemporal_load(&qmu[j1]);
            f32x4 nd1 = qsig[j1];
            acc += kl4(a0, b0, c0, d0);
            acc += kl4(a1, b1, c1, d1);
            a0 = na0; b0 = nb0; c0 = nc0; d0 = nd0;
            a1 = na1; b1 = nb1; c1 = nc1; d1 = nd1;
            i = j0; k = j1;
        }
        acc += kl4(a0, b0, c0, d0);
        acc += kl4(a1, b1, c1, d1);
    }
    // remainder (empty at the reference shape)
    for (long i = full * step2 + idx; i < n4; i += stride) {
        acc += kl4(pmu[i], psig[i], qmu[i], qsig[i]);
    }

    acc = wave_reduce_sum(acc);
    __shared__ float smem[RED_THREADS / 64];
    int lane = threadIdx.x & 63;
    int wid  = threadIdx.x >> 6;
    if (lane == 0) smem[wid] = acc;
    __syncthreads();
    if (threadIdx.x == 0) {
        float s = 0.0f;
        #pragma unroll
        for (int w = 0; w < RED_THREADS / 64; ++w) s += smem[w];
        partial[blockIdx.x] = s;
    }
}

__global__ __launch_bounds__(RED_THREADS) void kl_final_kernel(
        const float* __restrict__ partial,
        float* __restrict__ out,
        int n, float scale) {
    float acc = 0.0f;
    for (int i = threadIdx.x; i < n; i += blockDim.x) acc += partial[i];
    acc = wave_reduce_sum(acc);
    __shared__ float smem[RED_THREADS / 64];
    int lane = threadIdx.x & 63;
    int wid  = threadIdx.x >> 6;
    if (lane == 0) smem[wid] = acc;
    __syncthreads();
    if (threadIdx.x == 0) {
        float s = 0.0f;
        #pragma unroll
        for (int w = 0; w < RED_THREADS / 64; ++w) s += smem[w];
        out[0] = s * scale;
    }
}

extern "C" void kernel_launch(void* const* d_in, const int* in_sizes, int n_in,
                              void* d_out, int out_size, void* d_ws, size_t ws_size,
                              hipStream_t stream) {
    const f32x4* pmu  = (const f32x4*)d_in[0];
    const f32x4* psig = (const f32x4*)d_in[1];
    const f32x4* qmu  = (const f32x4*)d_in[2];
    const f32x4* qsig = (const f32x4*)d_in[3];

    long n  = (long)in_sizes[0];
    long n4 = n / 4;

    float* partial = (float*)d_ws;
    float* out     = (float*)d_out;

    const float scale = 1.0f / 1024.0f;  // 1/(B*L)

    kl_partial_kernel<<<RED_BLOCKS, RED_THREADS, 0, stream>>>(
        pmu, psig, qmu, qsig, partial, n4);
    kl_final_kernel<<<1, RED_THREADS, 0, stream>>>(
        partial, out, RED_BLOCKS, scale);
}

// Round 5
// 86.440 us; speedup vs baseline: 1.0193x; 1.0193x over previous
//
#include <hip/hip_runtime.h>

// KL(p||q) diagonal Gaussians -> scalar:
//   out = (1/(B*L)) * sum [ 0.5*( (sp^2+(mp-mq)^2)/sq^2 - log(sp^2/sq^2) - 1 ) ]
// 4 fp32 tensors x 33,554,432 elems = 512 MiB read, irreducible.
// Round-3 structure (best: 85.9 us = 99.4% of 6.29 TB/s streaming ceiling):
//   - 1-deep register prefetch, VGPR 24 -> full occupancy
//   - nt loads on mu streams -> sigma tensors (256 MiB) stay L3-resident
//     (FETCH_SIZE == mu bytes only)
//   - single log + single rcp per element
// Round 4's 2x unroll regressed (occupancy 65->51%): bandwidth-capped at
// ~10.2 B/cyc/CU through the CU<->fabric path; L3 hits share that path.

#define RED_BLOCKS 2048
#define RED_THREADS 256

typedef float f32x4 __attribute__((ext_vector_type(4)));

__device__ __forceinline__ float wave_reduce_sum(float v) {
    #pragma unroll
    for (int off = 32; off > 0; off >>= 1)
        v += __shfl_down(v, off, 64);
    return v;
}

// per-float4 KL contribution (single log + single rcp per element)
__device__ __forceinline__ float kl4(f32x4 mp, f32x4 sp, f32x4 mq, f32x4 sq) {
    float acc = 0.0f;
    #pragma unroll
    for (int k = 0; k < 4; ++k) {
        float sp2 = sp[k] * sp[k];
        float sq2 = sq[k] * sq[k];
        float d   = mp[k] - mq[k];
        float inv = __frcp_rn(sq2);
        acc += (sp2 + d * d) * inv - __logf(sp2 * inv) - 1.0f;
    }
    return 0.5f * acc;
}

__global__ __launch_bounds__(RED_THREADS) void kl_partial_kernel(
        const f32x4* __restrict__ pmu,
        const f32x4* __restrict__ psig,
        const f32x4* __restrict__ qmu,
        const f32x4* __restrict__ qsig,
        float* __restrict__ partial,
        long n4) {
    long idx    = (long)blockIdx.x * blockDim.x + threadIdx.x;
    long stride = (long)gridDim.x * blockDim.x;

    float acc = 0.0f;

    long full_iters = n4 / stride;           // 16 at the reference shape
    if (full_iters > 0) {
        long i = idx;
        // mu streams: non-temporal (no L3 pollution); sigma streams: cached.
        f32x4 a = __builtin_nontemporal_load(&pmu[i]);
        f32x4 b = psig[i];
        f32x4 c = __builtin_nontemporal_load(&qmu[i]);
        f32x4 d = qsig[i];
        for (long it = 0; it < full_iters - 1; ++it) {
            long j = i + stride;
            f32x4 a1 = __builtin_nontemporal_load(&pmu[j]);
            f32x4 b1 = psig[j];
            f32x4 c1 = __builtin_nontemporal_load(&qmu[j]);
            f32x4 d1 = qsig[j];
            acc += kl4(a, b, c, d);
            a = a1; b = b1; c = c1; d = d1;
            i = j;
        }
        acc += kl4(a, b, c, d);
    }
    // remainder (empty at the reference shape, kept for generality)
    for (long i = full_iters * stride + idx; i < n4; i += stride) {
        acc += kl4(pmu[i], psig[i], qmu[i], qsig[i]);
    }

    acc = wave_reduce_sum(acc);
    __shared__ float smem[RED_THREADS / 64];
    int lane = threadIdx.x & 63;
    int wid  = threadIdx.x >> 6;
    if (lane == 0) smem[wid] = acc;
    __syncthreads();
    if (threadIdx.x == 0) {
        float s = 0.0f;
        #pragma unroll
        for (int w = 0; w < RED_THREADS / 64; ++w) s += smem[w];
        partial[blockIdx.x] = s;
    }
}

__global__ __launch_bounds__(RED_THREADS) void kl_final_kernel(
        const float* __restrict__ partial,
        float* __restrict__ out,
        int n, float scale) {
    float acc = 0.0f;
    for (int i = threadIdx.x; i < n; i += blockDim.x) acc += partial[i];
    acc = wave_reduce_sum(acc);
    __shared__ float smem[RED_THREADS / 64];
    int lane = threadIdx.x & 63;
    int wid  = threadIdx.x >> 6;
    if (lane == 0) smem[wid] = acc;
    __syncthreads();
    if (threadIdx.x == 0) {
        float s = 0.0f;
        #pragma unroll
        for (int w = 0; w < RED_THREADS / 64; ++w) s += smem[w];
        out[0] = s * scale;
    }
}

extern "C" void kernel_launch(void* const* d_in, const int* in_sizes, int n_in,
                              void* d_out, int out_size, void* d_ws, size_t ws_size,
                              hipStream_t stream) {
    const f32x4* pmu  = (const f32x4*)d_in[0];
    const f32x4* psig = (const f32x4*)d_in[1];
    const f32x4* qmu  = (const f32x4*)d_in[2];
    const f32x4* qsig = (const f32x4*)d_in[3];

    long n  = (long)in_sizes[0];
    long n4 = n / 4;

    float* partial = (float*)d_ws;
    float* out     = (float*)d_out;

    const float scale = 1.0f / 1024.0f;  // 1/(B*L)

    kl_partial_kernel<<<RED_BLOCKS, RED_THREADS, 0, stream>>>(
        pmu, psig, qmu, qsig, partial, n4);
    kl_final_kernel<<<1, RED_THREADS, 0, stream>>>(
        partial, out, RED_BLOCKS, scale);
}